// Round 3
// baseline (460.304 us; speedup 1.0000x reference)
//
#include <hip/hip_runtime.h>
#include <hip/hip_cooperative_groups.h>

namespace cg = cooperative_groups;

#define NN 2048
#define KTOP 256
#define INV_EPS 1000.0f
#define WIN 0.33f   // 1000*WIN^2 = 108.9 > 88 + max|potential| (15.3) -> dropped terms underflow
#define NB 32       // blocks per batch
#define CHUNK 64    // outputs per block per phase (NN / NB)

// ---------------------------------------------------------------------------
// Fully fused Sinkhorn top-K:
//   phase 0: rank-sort s -> t (descending)           [grid sync]
//   phase 1: c_j  = log sum_i exp(-1000(t_i-t_j)^2)             [grid sync]
//   phase 2: r_i  = log sum_j exp(-1000(t_i-t_j)^2 - c_j)       [grid sync]
//   phase 3: cc_j = log sum_i exp(-1000(t_i-t_j)^2 - r_i)       [grid sync]
//   phase 4: out_i = LSE_{j<K}(g) - LSE_j(g), g = -1000(s_i-t_j)^2 - cc_j
// All potentials are windowed (+-WIN in value space): dropped terms are
// < e^-93 relative to a kept term >= e^-15.3 -> below fp32 denormals.
// t stays resident in LDS across phases 1-4; only the 8KB aux row re-stages.
// ---------------------------------------------------------------------------
__global__ __launch_bounds__(256) void fused_k(const float* __restrict__ s,
                                               float* __restrict__ t,
                                               float* __restrict__ c,
                                               float* __restrict__ r,
                                               float* __restrict__ cc,
                                               float* __restrict__ out) {
    cg::grid_group grid = cg::this_grid();
    __shared__ float lt[NN];   // sorted t (persists phases 1-4)
    __shared__ float la[NN];   // per-phase aux (s, then c, r, cc)

    const int b     = blockIdx.x >> 5;       // batch
    const int chnk  = blockIdx.x & 31;       // chunk of 64 outputs
    const int obase = chnk * CHUNK;
    const int tid   = threadIdx.x;
    const int o     = obase + (tid >> 2);    // this thread's output (4 lanes each)
    const int ln    = tid & 3;

    // ---------------- phase 0: rank sort ----------------
    {
        const float4* sv = (const float4*)(s + (size_t)b * NN);
        float4* lav = (float4*)la;
        for (int k = tid; k < NN / 4; k += 256) lav[k] = sv[k];
        __syncthreads();
        const float x = la[o];
        const float4* lv = (const float4*)la;
        int cnt = 0;
        for (int k4 = ln; k4 < NN / 4; k4 += 4) {
            float4 v = lv[k4];
            int kb = k4 << 2;
            cnt += (v.x > x) || (v.x == x && (kb + 0) < o);
            cnt += (v.y > x) || (v.y == x && (kb + 1) < o);
            cnt += (v.z > x) || (v.z == x && (kb + 2) < o);
            cnt += (v.w > x) || (v.w == x && (kb + 3) < o);
        }
        cnt += __shfl_xor(cnt, 1);
        cnt += __shfl_xor(cnt, 2);
        if (ln == 0) t[(size_t)b * NN + cnt] = x;
    }
    grid.sync();

    // stage sorted t once; persists for all remaining phases
    {
        const float4* tv = (const float4*)(t + (size_t)b * NN);
        float4* ltv = (float4*)lt;
        for (int k = tid; k < NN / 4; k += 256) ltv[k] = tv[k];
        __syncthreads();
    }

    // ---------------- phase 1: c (no aux) ----------------
    {
        const float x = lt[o];
        int lo, hi;
        { int l = 0, rr = NN; while (l < rr) { int m = (l + rr) >> 1; if (lt[m] < x + WIN) rr = m; else l = m + 1; } lo = l; }
        { int l = 0, rr = NN; while (l < rr) { int m = (l + rr) >> 1; if (lt[m] <= x - WIN) rr = m; else l = m + 1; } hi = l; }
        float acc = 0.f;
        for (int j = lo + ln; j < hi; j += 4) {
            float d = x - lt[j];
            acc += __expf(-INV_EPS * d * d);
        }
        acc += __shfl_xor(acc, 1);
        acc += __shfl_xor(acc, 2);
        if (ln == 0) c[(size_t)b * NN + o] = __logf(acc);
    }
    grid.sync();

    // ---------------- phase 2: r (aux = c) ----------------
    {
        const float4* av = (const float4*)(c + (size_t)b * NN);
        float4* lav = (float4*)la;
        for (int k = tid; k < NN / 4; k += 256) lav[k] = av[k];
        __syncthreads();
        const float x = lt[o];
        int lo, hi;
        { int l = 0, rr = NN; while (l < rr) { int m = (l + rr) >> 1; if (lt[m] < x + WIN) rr = m; else l = m + 1; } lo = l; }
        { int l = 0, rr = NN; while (l < rr) { int m = (l + rr) >> 1; if (lt[m] <= x - WIN) rr = m; else l = m + 1; } hi = l; }
        float acc = 0.f;
        for (int j = lo + ln; j < hi; j += 4) {
            float d = x - lt[j];
            acc += __expf(fmaf(-INV_EPS * d, d, -la[j]));
        }
        acc += __shfl_xor(acc, 1);
        acc += __shfl_xor(acc, 2);
        if (ln == 0) r[(size_t)b * NN + o] = __logf(acc);
    }
    grid.sync();

    // ---------------- phase 3: cc (aux = r) ----------------
    {
        const float4* av = (const float4*)(r + (size_t)b * NN);
        float4* lav = (float4*)la;
        __syncthreads();   // ensure phase-2 reads of la are done before overwrite
        for (int k = tid; k < NN / 4; k += 256) lav[k] = av[k];
        __syncthreads();
        const float x = lt[o];
        int lo, hi;
        { int l = 0, rr = NN; while (l < rr) { int m = (l + rr) >> 1; if (lt[m] < x + WIN) rr = m; else l = m + 1; } lo = l; }
        { int l = 0, rr = NN; while (l < rr) { int m = (l + rr) >> 1; if (lt[m] <= x - WIN) rr = m; else l = m + 1; } hi = l; }
        float acc = 0.f;
        for (int j = lo + ln; j < hi; j += 4) {
            float d = x - lt[j];
            acc += __expf(fmaf(-INV_EPS * d, d, -la[j]));
        }
        acc += __shfl_xor(acc, 1);
        acc += __shfl_xor(acc, 2);
        if (ln == 0) cc[(size_t)b * NN + o] = __logf(acc);
    }
    grid.sync();

    // ---------------- phase 4: out (aux = cc, original index space) ----------------
    {
        const float4* av = (const float4*)(cc + (size_t)b * NN);
        float4* lav = (float4*)la;
        __syncthreads();
        for (int k = tid; k < NN / 4; k += 256) lav[k] = av[k];
        __syncthreads();
        const float x = s[(size_t)b * NN + o];

        // top-K max (can be ~-2e4 -> explicit max tracking)
        float m = -3.4e38f;
        for (int j = ln; j < KTOP; j += 4) {
            float d = x - lt[j];
            m = fmaxf(m, fmaf(-INV_EPS * d, d, -la[j]));
        }
        m = fmaxf(m, __shfl_xor(m, 1));
        m = fmaxf(m, __shfl_xor(m, 2));

        // top-K sum, max-subtracted
        float part = 0.f;
        for (int j = ln; j < KTOP; j += 4) {
            float d = x - lt[j];
            part += __expf(fmaf(-INV_EPS * d, d, -la[j]) - m);
        }
        part += __shfl_xor(part, 1);
        part += __shfl_xor(part, 2);

        // full-row windowed sum (matching term >= e^-15.3 -> naive sum stable)
        int lo, hi;
        { int l = 0, rr = NN; while (l < rr) { int mm = (l + rr) >> 1; if (lt[mm] < x + WIN) rr = mm; else l = mm + 1; } lo = l; }
        { int l = 0, rr = NN; while (l < rr) { int mm = (l + rr) >> 1; if (lt[mm] <= x - WIN) rr = mm; else l = mm + 1; } hi = l; }
        float acc = 0.f;
        for (int j = lo + ln; j < hi; j += 4) {
            float d = x - lt[j];
            acc += __expf(fmaf(-INV_EPS * d, d, -la[j]));
        }
        acc += __shfl_xor(acc, 1);
        acc += __shfl_xor(acc, 2);

        if (ln == 0) out[(size_t)b * NN + o] = m + __logf(part) - __logf(acc);
    }
}

extern "C" void kernel_launch(void* const* d_in, const int* in_sizes, int n_in,
                              void* d_out, int out_size, void* d_ws, size_t ws_size,
                              hipStream_t stream) {
    const float* s = (const float*)d_in[0];
    float* out = (float*)d_out;
    const int total = in_sizes[0];
    const int Bn = total / NN;            // 32 batches

    float* ws = (float*)d_ws;
    float* t  = ws;
    float* c  = ws + (size_t)Bn * NN;
    float* r  = ws + 2 * (size_t)Bn * NN;
    float* cc = ws + 3 * (size_t)Bn * NN;

    void* args[] = {(void*)&s, (void*)&t, (void*)&c, (void*)&r, (void*)&cc, (void*)&out};
    dim3 grid(Bn * NB), block(256);
    hipLaunchCooperativeKernel((const void*)fused_k, grid, block, args, 0, stream);
}

// Round 4
// 118.387 us; speedup vs baseline: 3.8881x; 3.8881x over previous
//
#include <hip/hip_runtime.h>

#define NN 2048
#define KTOP 256
#define WIN 0.22f          // value-space window; 1000*WIN^2 = 48.4 nats = 69.8 bits
#define KE 1442.6951f      // 1000 * log2(e): exp(-1000 d^2) = 2^(-KE d^2)
#define LN2 0.69314718f
#define MARG2 0.048f       // value^2 margin for top-K window (~48 nats)

// ---------------------------------------------------------------------------
// Rank sort (8 lanes per element). Writes (value, 0) pairs in sorted order
// plus the inverse permutation for the final scatter.
// ---------------------------------------------------------------------------
__global__ __launch_bounds__(256) void rank_sort_k(const float* __restrict__ s,
                                                   float2* __restrict__ pairs,
                                                   int* __restrict__ iperm) {
    __shared__ float ls[NN];
    const int b = blockIdx.x >> 6;                // 64 blocks/batch
    const int obase = (blockIdx.x & 63) << 5;     // 32 elements/block
    const int tid = threadIdx.x;
    const float4* sv = (const float4*)(s + (size_t)b * NN);
    float4* lv4 = (float4*)ls;
    for (int k = tid; k < NN / 4; k += 256) lv4[k] = sv[k];
    __syncthreads();
    const int o = obase + (tid >> 3);
    const int ch = tid & 7;
    const float x = ls[o];
    const float4* lv = (const float4*)ls;
    int cnt = 0;
    for (int k4 = ch; k4 < NN / 4; k4 += 8) {
        float4 v = lv[k4];
        int kb = k4 << 2;
        cnt += (v.x > x) || (v.x == x && (kb + 0) < o);
        cnt += (v.y > x) || (v.y == x && (kb + 1) < o);
        cnt += (v.z > x) || (v.z == x && (kb + 2) < o);
        cnt += (v.w > x) || (v.w == x && (kb + 3) < o);
    }
    cnt += __shfl_xor(cnt, 1);
    cnt += __shfl_xor(cnt, 2);
    cnt += __shfl_xor(cnt, 4);
    if (ch == 0) {
        pairs[(size_t)b * NN + cnt] = make_float2(x, 0.f);
        iperm[(size_t)b * NN + cnt] = o;
    }
}

// ---------------------------------------------------------------------------
// Potential pass: pout[o] = (t_o, -log2 sum_j 2^(-KE*(t_o-t_j)^2 + y_j)).
// Wave = 64 consecutive sorted outputs; union window; all LDS reads broadcast.
// ---------------------------------------------------------------------------
__global__ __launch_bounds__(256) void pot_k(const float2* __restrict__ pin,
                                             float2* __restrict__ pout) {
    __shared__ float2 lp[NN];
    const int b = blockIdx.x >> 3;                // 8 blocks/batch
    const int obase = (blockIdx.x & 7) << 8;      // 256 outputs/block
    const int tid = threadIdx.x;
    const float2* src = pin + (size_t)b * NN;
    for (int k = tid; k < NN; k += 256) lp[k] = src[k];
    __syncthreads();
    const int o = obase + tid;
    const float x = lp[o].x;
    const int wb = obase + (tid & ~63);           // wave's first (largest) output
    const float bhi = lp[wb].x + WIN;
    const float blo = lp[wb + 63].x - WIN;
    int l0 = 0, r0 = NN, l1 = 0, r1 = NN;
#pragma unroll
    for (int it = 0; it < 11; ++it) {             // two uniform binary searches
        int m0 = (l0 + r0) >> 1; bool c0 = lp[m0].x < bhi;  r0 = c0 ? m0 : r0; l0 = c0 ? l0 : m0 + 1;
        int m1 = (l1 + r1) >> 1; bool c1 = lp[m1].x <= blo; r1 = c1 ? m1 : r1; l1 = c1 ? l1 : m1 + 1;
    }
    const int lo = l0, hi = l1;
    float a0 = 0.f, a1 = 0.f;
    int j = lo;
    for (; j + 2 <= hi; j += 2) {
        float2 p0 = lp[j], p1 = lp[j + 1];
        float d0 = x - p0.x, d1 = x - p1.x;
        a0 += exp2f(fmaf(-KE * d0, d0, p0.y));
        a1 += exp2f(fmaf(-KE * d1, d1, p1.y));
    }
    if (j < hi) { float2 p = lp[j]; float d = x - p.x; a0 += exp2f(fmaf(-KE * d, d, p.y)); }
    pout[(size_t)b * NN + o] = make_float2(x, -log2f(a0 + a1));
}

// ---------------------------------------------------------------------------
// Final pass (sorted space, scatter to original order):
//   out = ln2 * ( log2 LSE_{j<K}(g) - log2 LSE_j(g) ),  g = -KE d^2 + y_j.
// o <  K : top-K part windowed & naive (its max >= 2^-22).
// o >= K : only the slice t_j in [t_{K-1}, x + sqrt(D^2+MARG2)] contributes;
//          explicit max tracking there (max ~ -1e5 possible).
// ---------------------------------------------------------------------------
__global__ __launch_bounds__(256) void topk_k(const float2* __restrict__ pin,
                                              const int* __restrict__ iperm,
                                              float* __restrict__ out) {
    __shared__ float2 lp[NN];
    const int b = blockIdx.x >> 3;
    const int obase = (blockIdx.x & 7) << 8;
    const int tid = threadIdx.x;
    const float2* src = pin + (size_t)b * NN;
    for (int k = tid; k < NN; k += 256) lp[k] = src[k];
    __syncthreads();
    const int o = obase + tid;
    const float x = lp[o].x;
    const int wb = obase + (tid & ~63);
    const float bhi = lp[wb].x + WIN;
    const float blo = lp[wb + 63].x - WIN;
    int l0 = 0, r0 = NN, l1 = 0, r1 = NN;
#pragma unroll
    for (int it = 0; it < 11; ++it) {
        int m0 = (l0 + r0) >> 1; bool c0 = lp[m0].x < bhi;  r0 = c0 ? m0 : r0; l0 = c0 ? l0 : m0 + 1;
        int m1 = (l1 + r1) >> 1; bool c1 = lp[m1].x <= blo; r1 = c1 ? m1 : r1; l1 = c1 ? l1 : m1 + 1;
    }
    const int lo = l0, hi = l1;

    // full-row sum (naive; matching term >= 2^-22)
    float a0 = 0.f, a1 = 0.f;
    int j = lo;
    for (; j + 2 <= hi; j += 2) {
        float2 p0 = lp[j], p1 = lp[j + 1];
        float d0 = x - p0.x, d1 = x - p1.x;
        a0 += exp2f(fmaf(-KE * d0, d0, p0.y));
        a1 += exp2f(fmaf(-KE * d1, d1, p1.y));
    }
    if (j < hi) { float2 p = lp[j]; float d = x - p.x; a0 += exp2f(fmaf(-KE * d, d, p.y)); }
    const float l2row = log2f(a0 + a1);

    float res2;
    if (o < KTOP) {                                // whole block uniform (K = 256)
        const int hk = min(hi, KTOP);
        float ps = 0.f;
        for (int jj = lo; jj < hk; ++jj) {
            float2 p = lp[jj];
            float d = x - p.x;
            ps += exp2f(fmaf(-KE * d, d, p.y));
        }
        res2 = log2f(ps) - l2row;
    } else {
        const float tK = lp[KTOP - 1].x;
        const float xwm = lp[wb].x;                // largest x in wave
        const float dwv = tK - xwm;                // >= 0
        const float vb = xwm + sqrtf(fmaf(dwv, dwv, MARG2));
        int l = 0, r = KTOP;
#pragma unroll
        for (int it = 0; it < 8; ++it) {           // uniform search in top-K slice
            int m = (l + r) >> 1; bool c = lp[m].x < vb; r = c ? m : r; l = c ? l : m + 1;
        }
        float mx = -3.4e38f;
        for (int jj = l; jj < KTOP; ++jj) {
            float2 p = lp[jj];
            float d = x - p.x;
            mx = fmaxf(mx, fmaf(-KE * d, d, p.y));
        }
        float ss = 0.f;
        for (int jj = l; jj < KTOP; ++jj) {
            float2 p = lp[jj];
            float d = x - p.x;
            ss += exp2f(fmaf(-KE * d, d, p.y) - mx);
        }
        res2 = mx + log2f(ss) - l2row;
    }
    out[(size_t)b * NN + iperm[(size_t)b * NN + o]] = LN2 * res2;
}

extern "C" void kernel_launch(void* const* d_in, const int* in_sizes, int n_in,
                              void* d_out, int out_size, void* d_ws, size_t ws_size,
                              hipStream_t stream) {
    const float* s = (const float*)d_in[0];
    float* out = (float*)d_out;
    const int Bn = in_sizes[0] / NN;              // 32 batches

    float2* A = (float2*)d_ws;                    // ping
    float2* B = A + (size_t)Bn * NN;              // pong
    int* iperm = (int*)(B + (size_t)Bn * NN);     // inverse permutation

    rank_sort_k<<<Bn * 64, 256, 0, stream>>>(s, A, iperm);  // sort -> (t, 0)
    pot_k<<<Bn * 8, 256, 0, stream>>>(A, B);                // c  (col norm 1)
    pot_k<<<Bn * 8, 256, 0, stream>>>(B, A);                // r  (row norm 1)
    pot_k<<<Bn * 8, 256, 0, stream>>>(A, B);                // cc (col norm 2)
    topk_k<<<Bn * 8, 256, 0, stream>>>(B, iperm, out);      // output + scatter
}

// Round 5
// 85.070 us; speedup vs baseline: 5.4109x; 1.3916x over previous
//
#include <hip/hip_runtime.h>

#define NN 2048
#define KTOP 256
#define WIN 0.25f          // value-space window; 1000*WIN^2 = 62.5 nats = 90 bits
#define KE 1442.6951f      // 1000 * log2(e): exp(-1000 d^2) = 2^(-KE d^2)
#define LN2 0.69314718f
#define MARG2 0.0625f      // value^2 margin for top-K numerator window (90 bits)
#define OPB 64             // outputs per block (pot/topk)

// ---------------------------------------------------------------------------
// Rank sort (8 lanes per element): writes (value, 0) pairs in sorted
// descending order plus the inverse permutation for the final scatter.
// 2048 blocks -> full occupancy. LDS reads: 8 distinct b128 addrs/wave
// x 4 banks = all 32 banks, same-addr groups broadcast -> conflict-free.
// ---------------------------------------------------------------------------
__global__ __launch_bounds__(256) void rank_sort_k(const float* __restrict__ s,
                                                   float2* __restrict__ pairs,
                                                   int* __restrict__ iperm) {
    __shared__ float ls[NN];
    const int b = blockIdx.x >> 6;                // 64 blocks/batch
    const int obase = (blockIdx.x & 63) << 5;     // 32 elements/block
    const int tid = threadIdx.x;
    const float4* sv = (const float4*)(s + (size_t)b * NN);
    float4* lv4 = (float4*)ls;
    for (int k = tid; k < NN / 4; k += 256) lv4[k] = sv[k];
    __syncthreads();
    const int o = obase + (tid >> 3);
    const int ch = tid & 7;
    const float x = ls[o];
    const float4* lv = (const float4*)ls;
    int cnt = 0;
    for (int k4 = ch; k4 < NN / 4; k4 += 8) {
        float4 v = lv[k4];
        int kb = k4 << 2;
        cnt += (v.x > x) || (v.x == x && (kb + 0) < o);
        cnt += (v.y > x) || (v.y == x && (kb + 1) < o);
        cnt += (v.z > x) || (v.z == x && (kb + 2) < o);
        cnt += (v.w > x) || (v.w == x && (kb + 3) < o);
    }
    cnt += __shfl_xor(cnt, 1);
    cnt += __shfl_xor(cnt, 2);
    cnt += __shfl_xor(cnt, 4);
    if (ch == 0) {
        pairs[(size_t)b * NN + cnt] = make_float2(x, 0.f);
        iperm[(size_t)b * NN + cnt] = o;
    }
}

// ---------------------------------------------------------------------------
// Potential pass: pout[o] = (t_o, -log2 sum_j 2^(-KE*(t_o-t_j)^2 + y_j)).
// Block = 4 waves x 64 outputs; the block-union window is split across the
// 4 waves (stride 4), partials combined via LDS. All lp reads broadcast.
// ---------------------------------------------------------------------------
__global__ __launch_bounds__(256) void pot_k(const float2* __restrict__ pin,
                                             float2* __restrict__ pout) {
    __shared__ float2 lp[NN];
    __shared__ float part[4][OPB];
    const int b = blockIdx.x >> 5;                // 32 blocks/batch
    const int obase = (blockIdx.x & 31) << 6;     // 64 outputs/block
    const int tid = threadIdx.x;
    const int w = tid >> 6, ln = tid & 63;
    const float4* src4 = (const float4*)(pin + (size_t)b * NN);
    float4* lp4 = (float4*)lp;
    for (int k = tid; k < NN / 2; k += 256) lp4[k] = src4[k];
    __syncthreads();
    const int o = obase + ln;
    const float x = lp[o].x;
    const float bhi = lp[obase].x + WIN;           // block max value + WIN
    const float blo = lp[obase + OPB - 1].x - WIN; // block min value - WIN
    int l0 = 0, r0 = NN, l1 = 0, r1 = NN;
#pragma unroll
    for (int it = 0; it < 11; ++it) {              // two uniform binary searches
        int m0 = (l0 + r0) >> 1; bool c0 = lp[m0].x < bhi;  r0 = c0 ? m0 : r0; l0 = c0 ? l0 : m0 + 1;
        int m1 = (l1 + r1) >> 1; bool c1 = lp[m1].x <= blo; r1 = c1 ? m1 : r1; l1 = c1 ? l1 : m1 + 1;
    }
    const int lo = l0, hi = l1;
    float a0 = 0.f, a1 = 0.f;
    int j = lo + w;
    for (; j + 4 < hi; j += 8) {                   // wave w: every 4th term, x2 unroll
        float2 p0 = lp[j], p1 = lp[j + 4];
        float d0 = x - p0.x, d1 = x - p1.x;
        a0 += exp2f(fmaf(-KE * d0, d0, p0.y));
        a1 += exp2f(fmaf(-KE * d1, d1, p1.y));
    }
    if (j < hi) { float2 p = lp[j]; float d = x - p.x; a0 += exp2f(fmaf(-KE * d, d, p.y)); }
    part[w][ln] = a0 + a1;
    __syncthreads();
    if (w == 0) {
        float a = (part[0][ln] + part[1][ln]) + (part[2][ln] + part[3][ln]);
        pout[(size_t)b * NN + o] = make_float2(x, -log2f(a));
    }
}

// ---------------------------------------------------------------------------
// Final pass (sorted space, scatter to original order):
//   out = ln2 * ( log2 LSE_{j<K}(g) - log2 LSE_j(g) ),  g = -KE d^2 + y_j.
// o <  K : num and den accumulated in one fused windowed loop (num max is the
//          matching term >= 2^-22 -> naive sums stable).
// o >= K : den as above; num over the slice t_j in [t_{K-1}, vb) with per-wave
//          (max, scaled sum) partials merged by rescaling.
// ---------------------------------------------------------------------------
__global__ __launch_bounds__(256) void topk_k(const float2* __restrict__ pin,
                                              const int* __restrict__ iperm,
                                              float* __restrict__ out) {
    __shared__ float2 lp[NN];
    __shared__ float pd[4][OPB];
    __shared__ float pn[4][OPB];
    __shared__ float pm[4][OPB];
    const int b = blockIdx.x >> 5;
    const int obase = (blockIdx.x & 31) << 6;
    const int tid = threadIdx.x;
    const int w = tid >> 6, ln = tid & 63;
    const float4* src4 = (const float4*)(pin + (size_t)b * NN);
    float4* lp4 = (float4*)lp;
    for (int k = tid; k < NN / 2; k += 256) lp4[k] = src4[k];
    const int o = obase + ln;
    int dst = 0;
    if (w == 0) dst = iperm[(size_t)b * NN + o];   // prefetch scatter index early
    __syncthreads();
    const float x = lp[o].x;
    const float bhi = lp[obase].x + WIN;
    const float blo = lp[obase + OPB - 1].x - WIN;
    int l0 = 0, r0 = NN, l1 = 0, r1 = NN;
#pragma unroll
    for (int it = 0; it < 11; ++it) {
        int m0 = (l0 + r0) >> 1; bool c0 = lp[m0].x < bhi;  r0 = c0 ? m0 : r0; l0 = c0 ? l0 : m0 + 1;
        int m1 = (l1 + r1) >> 1; bool c1 = lp[m1].x <= blo; r1 = c1 ? m1 : r1; l1 = c1 ? l1 : m1 + 1;
    }
    const int lo = l0, hi = l1;
    const bool isTop = (obase + OPB <= KTOP);      // block-uniform (K multiple of 64)

    if (isTop) {
        float ad = 0.f, an = 0.f;
        for (int j = lo + w; j < hi; j += 4) {
            float2 p = lp[j];
            float d = x - p.x;
            float t = exp2f(fmaf(-KE * d, d, p.y));
            ad += t;
            an += (j < KTOP) ? t : 0.f;
        }
        pd[w][ln] = ad; pn[w][ln] = an;
        __syncthreads();
        if (w == 0) {
            float den = (pd[0][ln] + pd[1][ln]) + (pd[2][ln] + pd[3][ln]);
            float num = (pn[0][ln] + pn[1][ln]) + (pn[2][ln] + pn[3][ln]);
            out[(size_t)b * NN + dst] = LN2 * (log2f(num) - log2f(den));
        }
    } else {
        // denominator: 4-way window split
        float ad = 0.f;
        for (int j = lo + w; j < hi; j += 4) {
            float2 p = lp[j];
            float d = x - p.x;
            ad += exp2f(fmaf(-KE * d, d, p.y));
        }
        pd[w][ln] = ad;
        // numerator window within top-K: t_j < vb contributes
        const float tK = lp[KTOP - 1].x;
        const float xwm = lp[obase].x;             // block's largest x (<= tK)
        const float dwv = tK - xwm;                // >= 0
        const float vb = xwm + sqrtf(fmaf(dwv, dwv, MARG2));
        int l = 0, r = KTOP;
#pragma unroll
        for (int it = 0; it < 8; ++it) {
            int m = (l + r) >> 1; bool c = lp[m].x < vb; r = c ? m : r; l = c ? l : m + 1;
        }
        float mx = -3.4e38f;
        for (int jj = l + w; jj < KTOP; jj += 4) {
            float2 p = lp[jj];
            float d = x - p.x;
            mx = fmaxf(mx, fmaf(-KE * d, d, p.y));
        }
        float ss = 0.f;
        for (int jj = l + w; jj < KTOP; jj += 4) {
            float2 p = lp[jj];
            float d = x - p.x;
            ss += exp2f(fmaf(-KE * d, d, p.y) - mx);
        }
        pn[w][ln] = ss; pm[w][ln] = mx;
        __syncthreads();
        if (w == 0) {
            float den = (pd[0][ln] + pd[1][ln]) + (pd[2][ln] + pd[3][ln]);
            float M = fmaxf(fmaxf(pm[0][ln], pm[1][ln]), fmaxf(pm[2][ln], pm[3][ln]));
            float num = pn[0][ln] * exp2f(pm[0][ln] - M) + pn[1][ln] * exp2f(pm[1][ln] - M)
                      + pn[2][ln] * exp2f(pm[2][ln] - M) + pn[3][ln] * exp2f(pm[3][ln] - M);
            out[(size_t)b * NN + dst] = LN2 * (M + log2f(num) - log2f(den));
        }
    }
}

extern "C" void kernel_launch(void* const* d_in, const int* in_sizes, int n_in,
                              void* d_out, int out_size, void* d_ws, size_t ws_size,
                              hipStream_t stream) {
    const float* s = (const float*)d_in[0];
    float* out = (float*)d_out;
    const int Bn = in_sizes[0] / NN;              // 32 batches

    float2* A = (float2*)d_ws;                    // ping
    float2* B = A + (size_t)Bn * NN;              // pong
    int* iperm = (int*)(B + (size_t)Bn * NN);     // inverse permutation

    rank_sort_k<<<Bn * 64, 256, 0, stream>>>(s, A, iperm);  // sort -> (t, 0)
    pot_k<<<Bn * 32, 256, 0, stream>>>(A, B);               // c  (col norm 1)
    pot_k<<<Bn * 32, 256, 0, stream>>>(B, A);               // r  (row norm 1)
    pot_k<<<Bn * 32, 256, 0, stream>>>(A, B);               // cc (col norm 2)
    topk_k<<<Bn * 32, 256, 0, stream>>>(B, iperm, out);     // output + scatter
}